// Round 5
// baseline (458.514 us; speedup 1.0000x reference)
//
#include <hip/hip_runtime.h>

typedef _Float16 half8 __attribute__((ext_vector_type(8)));
typedef float floatx4 __attribute__((ext_vector_type(4)));
typedef int intx4 __attribute__((ext_vector_type(4)));

#define MFMA16(a, b, c) __builtin_amdgcn_mfma_f32_16x16x32_f16(a, b, c, 0, 0, 0)

static __device__ __forceinline__ half8 asH8(intx4 v) {
  half8 r;
  __builtin_memcpy(&r, &v, 16);
  return r;
}

static constexpr int kC = 64, kH = 64, kW = 64;
static constexpr int kM = 512, kD = 576;  // D = C*9
// ws layout (f16 elements):
//   WS1 (GEMM1 B, hi/lo interleaved per k-octet): [m:512][k8:72][16]
//   WS2 (GEMM2 B, hi only): [d:576][m:512]
static constexpr int WS2 = 589824;
// total ws: 884736 f16 = 1,769,472 bytes

__global__ void prep_split(const float* __restrict__ mem, _Float16* __restrict__ ws) {
  const int m = blockIdx.x;   // 512
  const int d = threadIdx.x;  // 576
  float v = mem[m * kD + d];
  _Float16 hi = (_Float16)v;
  _Float16 lo = (_Float16)(v - (float)hi);
  ws[m * 1152 + ((d >> 3) << 4) + (d & 7)] = hi;
  ws[m * 1152 + ((d >> 3) << 4) + (d & 7) + 8] = lo;
  ws[WS2 + d * 512 + m] = hi;
}

// One block: 32 pixels (b, h, w0..w0+31). 4 waves.
__global__ __launch_bounds__(256, 2) void mem_branch_kernel(
    const float* __restrict__ x, const float* __restrict__ temperature,
    const _Float16* __restrict__ ws, float* __restrict__ out) {
  // GEMM1 A fragments: [36 combos (kt*2+rt)][64 lanes][8 f16]; hi at 0, lo at +18432.
  // Later aliased by att-hi fragments: [32 combos (kt2*2+rt)][64][8] at base 0.
  __shared__ __align__(16) _Float16 afrag[36 * 64 * 8 * 2];
  __shared__ __align__(16) int tab[kD];
  __shared__ float red_max[4][32];
  __shared__ float red_sum[4][32];

  const int tid = threadIdx.x;
  const int lane = tid & 63;
  const int wv = tid >> 6;
  const int l15 = lane & 15;
  const int koct = lane >> 4;  // 0..3
  const int bx = blockIdx.x;
  const int b = bx >> 7;
  const int h = (bx >> 1) & 63;
  const int w0 = (bx & 1) << 5;

  const float sfac = temperature[0] * 0.060112293370373475f;  // (1/24)*log2(e)
  const _Float16* wsp = ws;

  for (int d = tid; d < kD; d += 256) {
    int c = d / 9, r9 = d % 9, kh = r9 / 3, kw = r9 % 3;
    tab[d] = (c << 12) + (kh << 6) + kw + (kh << 20) + (kw << 24);
  }
  __syncthreads();

  // ---- build patch A-fragments (hi/lo f16) directly in fragment layout ----
  {
    const int base0 = ((b * kC) * kH + (h - 1)) * kW + (w0 - 1);
    for (int combo = wv; combo < 36; combo += 4) {
      const int kt = combo >> 1, rt = combo & 1;
      const int pp = rt * 16 + l15;  // pixel 0..31
      const int dbase = kt * 32 + koct * 8;
      intx4 t0 = *reinterpret_cast<const intx4*>(&tab[dbase]);
      intx4 t1 = *reinterpret_cast<const intx4*>(&tab[dbase + 4]);
      half8 hv, lv;
#pragma unroll
      for (int j = 0; j < 8; ++j) {
        int t = (j < 4) ? t0[j] : t1[j - 4];
        int off = t & 0xFFFFF;
        int kh = (t >> 20) & 15;
        int kw = (t >> 24) & 15;
        bool ok = ((unsigned)(h - 1 + kh) < 64u) && ((unsigned)(w0 + pp - 1 + kw) < 64u);
        int idx = ok ? (base0 + pp + off) : 0;
        float v = __builtin_nontemporal_load(&x[idx]);
        v = ok ? v : 0.0f;
        _Float16 hi = (_Float16)v;
        hv[j] = hi;
        lv[j] = (_Float16)(v - (float)hi);
      }
      *reinterpret_cast<half8*>(&afrag[(combo * 64 + lane) * 8]) = hv;
      *reinterpret_cast<half8*>(&afrag[18432 + (combo * 64 + lane) * 8]) = lv;
    }
  }
  __syncthreads();

// ---- asm helpers ----
#define GLD16(dst, voff) \
  asm volatile("global_load_dwordx4 %0, %1, %2 offset:0" : "=v"(dst) : "v"(voff), "s"(wsp))
#define GLD16O(dst, voff) \
  asm volatile("global_load_dwordx4 %0, %1, %2 offset:16" : "=v"(dst) : "v"(voff), "s"(wsp))
#define VMW(N)                                            \
  do {                                                    \
    asm volatile("s_waitcnt vmcnt(" #N ")" ::: "memory"); \
    __builtin_amdgcn_sched_barrier(0);                    \
  } while (0)

  // ---- GEMM1: wave owns m in [wv*128, +128); ring-4 of half-kt bufs, distance 3.
  // Per-block staggered kt start (s1) decorrelates L2 line access across blocks.
  floatx4 acc[2][8];
  const floatx4 zed = {0.0f, 0.0f, 0.0f, 0.0f};
#pragma unroll
  for (int rt = 0; rt < 2; ++rt)
#pragma unroll
    for (int mt = 0; mt < 8; ++mt) acc[rt][mt] = zed;
  {
    const int s1 = bx % 18;
    int koI = s1 * 128;    // issue byte-offset (kt*128), wraps at 2304
    int aeU = s1 * 1024;   // A-frag element offset (kt*1024), wraps at 18432
    const int mrow = wv * 128 + l15;
    int vb[8];
#pragma unroll
    for (int mt = 0; mt < 8; ++mt) vb[mt] = (mrow + mt * 16) * 2304 + koct * 32;
    intx4 Q00, Q01, Q02, Q03, Q04, Q05, Q06, Q07;
    intx4 Q10, Q11, Q12, Q13, Q14, Q15, Q16, Q17;
    intx4 Q20, Q21, Q22, Q23, Q24, Q25, Q26, Q27;
    intx4 Q30, Q31, Q32, Q33, Q34, Q35, Q36, Q37;
    half8 ah0, ah1, al0, al1;

#define ADVK1 do { koI += 128; if (koI >= 2304) koI -= 2304; } while (0)
#define ADVA1 do { aeU += 1024; if (aeU >= 18432) aeU -= 18432; } while (0)

#define G1_AREAD                                                            \
  do {                                                                      \
    ah0 = *reinterpret_cast<const half8*>(&afrag[aeU + lane * 8]);          \
    ah1 = *reinterpret_cast<const half8*>(&afrag[aeU + 512 + lane * 8]);    \
    al0 = *reinterpret_cast<const half8*>(&afrag[18432 + aeU + lane * 8]);  \
    al1 = *reinterpret_cast<const half8*>(&afrag[18432 + aeU + 512 + lane * 8]); \
  } while (0)

#define G1_ISSUE(B, HALF)                                       \
  do {                                                          \
    int v0 = vb[(HALF)*4 + 0] + koI;                            \
    GLD16(Q##B##0, v0); GLD16O(Q##B##1, v0);                    \
    int v1 = vb[(HALF)*4 + 1] + koI;                            \
    GLD16(Q##B##2, v1); GLD16O(Q##B##3, v1);                    \
    int v2 = vb[(HALF)*4 + 2] + koI;                            \
    GLD16(Q##B##4, v2); GLD16O(Q##B##5, v2);                    \
    int v3 = vb[(HALF)*4 + 3] + koI;                            \
    GLD16(Q##B##6, v3); GLD16O(Q##B##7, v3);                    \
  } while (0)

#define G1_FMA(B, HALF)                                                  \
  do {                                                                   \
    const int m0 = (HALF)*4, m1 = m0 + 1, m2 = m0 + 2, m3 = m0 + 3;      \
    __builtin_amdgcn_s_setprio(1);                                       \
    acc[0][m0] = MFMA16(ah0, asH8(Q##B##0), acc[0][m0]);                 \
    acc[1][m0] = MFMA16(ah1, asH8(Q##B##0), acc[1][m0]);                 \
    acc[0][m1] = MFMA16(ah0, asH8(Q##B##2), acc[0][m1]);                 \
    acc[1][m1] = MFMA16(ah1, asH8(Q##B##2), acc[1][m1]);                 \
    acc[0][m2] = MFMA16(ah0, asH8(Q##B##4), acc[0][m2]);                 \
    acc[1][m2] = MFMA16(ah1, asH8(Q##B##4), acc[1][m2]);                 \
    acc[0][m3] = MFMA16(ah0, asH8(Q##B##6), acc[0][m3]);                 \
    acc[1][m3] = MFMA16(ah1, asH8(Q##B##6), acc[1][m3]);                 \
    acc[0][m0] = MFMA16(ah0, asH8(Q##B##1), acc[0][m0]);                 \
    acc[1][m0] = MFMA16(ah1, asH8(Q##B##1), acc[1][m0]);                 \
    acc[0][m1] = MFMA16(ah0, asH8(Q##B##3), acc[0][m1]);                 \
    acc[1][m1] = MFMA16(ah1, asH8(Q##B##3), acc[1][m1]);                 \
    acc[0][m2] = MFMA16(ah0, asH8(Q##B##5), acc[0][m2]);                 \
    acc[1][m2] = MFMA16(ah1, asH8(Q##B##5), acc[1][m2]);                 \
    acc[0][m3] = MFMA16(ah0, asH8(Q##B##7), acc[0][m3]);                 \
    acc[1][m3] = MFMA16(ah1, asH8(Q##B##7), acc[1][m3]);                 \
    acc[0][m0] = MFMA16(al0, asH8(Q##B##0), acc[0][m0]);                 \
    acc[1][m0] = MFMA16(al1, asH8(Q##B##0), acc[1][m0]);                 \
    acc[0][m1] = MFMA16(al0, asH8(Q##B##2), acc[0][m1]);                 \
    acc[1][m1] = MFMA16(al1, asH8(Q##B##2), acc[1][m1]);                 \
    acc[0][m2] = MFMA16(al0, asH8(Q##B##4), acc[0][m2]);                 \
    acc[1][m2] = MFMA16(al1, asH8(Q##B##4), acc[1][m2]);                 \
    acc[0][m3] = MFMA16(al0, asH8(Q##B##6), acc[0][m3]);                 \
    acc[1][m3] = MFMA16(al1, asH8(Q##B##6), acc[1][m3]);                 \
    __builtin_amdgcn_s_setprio(0);                                       \
  } while (0)

    // prologue: bufs 0,1 <- kt(s) halves; buf2 <- kt(s+1) half0
    G1_ISSUE(0, 0);
    G1_ISSUE(1, 1);
    ADVK1;
    G1_ISSUE(2, 0);
    for (int g = 0; g < 8; ++g) {
      G1_AREAD;  // A for kt 2g (rel)
      G1_ISSUE(3, 1); VMW(24); G1_FMA(0, 0);
      ADVK1;
      G1_ISSUE(0, 0); VMW(24); G1_FMA(1, 1);
      G1_ISSUE(1, 1); VMW(24);
      ADVA1; G1_AREAD;  // A for kt 2g+1
      G1_FMA(2, 0);
      ADVK1;
      G1_ISSUE(2, 0); VMW(24); G1_FMA(3, 1);
      ADVA1;  // -> kt 2g+2
    }
    // tail: A at kt16(rel), koI at kt17(rel)
    G1_AREAD;
    G1_ISSUE(3, 1); VMW(24); G1_FMA(0, 0);
    VMW(16); G1_FMA(1, 1);
    ADVA1; G1_AREAD;
    VMW(8); G1_FMA(2, 0);
    VMW(0); G1_FMA(3, 1);
  }

  // ---- softmax over m (512); lane: p = rt*16+koct*4+r, m = wv*128+mt*16+l15 ----
  float pm[2][4], ps[2][4], gm[2][4], rinv[2][4];
#pragma unroll
  for (int rt = 0; rt < 2; ++rt)
#pragma unroll
    for (int r = 0; r < 4; ++r) {
      float v = acc[rt][0][r];
#pragma unroll
      for (int mt = 1; mt < 8; ++mt) v = fmaxf(v, acc[rt][mt][r]);
      pm[rt][r] = v;
    }
#pragma unroll
  for (int off = 1; off < 16; off <<= 1)
#pragma unroll
    for (int rt = 0; rt < 2; ++rt)
#pragma unroll
      for (int r = 0; r < 4; ++r) pm[rt][r] = fmaxf(pm[rt][r], __shfl_xor(pm[rt][r], off, 64));
  if (l15 == 0) {
#pragma unroll
    for (int rt = 0; rt < 2; ++rt)
#pragma unroll
      for (int r = 0; r < 4; ++r) red_max[wv][rt * 16 + koct * 4 + r] = pm[rt][r];
  }
  __syncthreads();
#pragma unroll
  for (int rt = 0; rt < 2; ++rt)
#pragma unroll
    for (int r = 0; r < 4; ++r) {
      int p = rt * 16 + koct * 4 + r;
      gm[rt][r] = fmaxf(fmaxf(red_max[0][p], red_max[1][p]), fmaxf(red_max[2][p], red_max[3][p]));
      ps[rt][r] = 0.0f;
    }
#pragma unroll
  for (int rt = 0; rt < 2; ++rt)
#pragma unroll
    for (int mt = 0; mt < 8; ++mt)
#pragma unroll
      for (int r = 0; r < 4; ++r) {
        float e = exp2f((acc[rt][mt][r] - gm[rt][r]) * sfac);
        acc[rt][mt][r] = e;
        ps[rt][r] += e;
      }
#pragma unroll
  for (int off = 1; off < 16; off <<= 1)
#pragma unroll
    for (int rt = 0; rt < 2; ++rt)
#pragma unroll
      for (int r = 0; r < 4; ++r) ps[rt][r] += __shfl_xor(ps[rt][r], off, 64);
  if (l15 == 0) {
#pragma unroll
    for (int rt = 0; rt < 2; ++rt)
#pragma unroll
      for (int r = 0; r < 4; ++r) red_sum[wv][rt * 16 + koct * 4 + r] = ps[rt][r];
  }
  __syncthreads();
#pragma unroll
  for (int rt = 0; rt < 2; ++rt)
#pragma unroll
    for (int r = 0; r < 4; ++r) {
      int p = rt * 16 + koct * 4 + r;
      rinv[rt][r] = 1.0f / (red_sum[0][p] + red_sum[1][p] + red_sum[2][p] + red_sum[3][p]);
    }
  // write att-hi fragments into (aliased) afrag
#pragma unroll
  for (int rt = 0; rt < 2; ++rt)
#pragma unroll
    for (int mt = 0; mt < 8; ++mt)
#pragma unroll
      for (int r = 0; r < 4; ++r) {
        float a = acc[rt][mt][r] * rinv[rt][r];
        _Float16 hi = (_Float16)a;
        int m = wv * 128 + mt * 16 + l15;
        int lf = (koct * 4 + r) + (((m >> 3) & 3) << 4);
        int idxe = ((((m >> 5) << 1) + rt) * 64 + lf) * 8 + (m & 7);
        afrag[idxe] = hi;
      }
  __syncthreads();

  // ---- GEMM2 (single-term): out[32][576] = att_hi @ mem_hi; wave owns d in [wv*144,+144).
  // Ring-3 of full-kt2 bufs, distance 2; staggered kt2 start (s2).
  floatx4 acc2[2][9];
#pragma unroll
  for (int rt = 0; rt < 2; ++rt)
#pragma unroll
    for (int nt = 0; nt < 9; ++nt) acc2[rt][nt] = zed;
  {
    const int s2 = bx & 15;
    int koI2 = s2 * 64;    // issue byte-offset (kt2*64), wraps at 1024
    int aeU2 = s2 * 1024;  // att-frag element offset (kt2*1024), wraps at 16384
    const int d0 = wv * 144 + l15;
    int vc[9];
#pragma unroll
    for (int nt = 0; nt < 9; ++nt) vc[nt] = WS2 * 2 + (d0 + nt * 16) * 1024 + koct * 16;
    intx4 T00, T01, T02, T03, T04, T05, T06, T07, T08;
    intx4 T10, T11, T12, T13, T14, T15, T16, T17, T18;
    intx4 T20, T21, T22, T23, T24, T25, T26, T27, T28;
    half8 a2h0, a2h1;

#define ADVK2 do { koI2 += 64; if (koI2 >= 1024) koI2 -= 1024; } while (0)
#define ADVA2 do { aeU2 += 1024; if (aeU2 >= 16384) aeU2 -= 16384; } while (0)

#define G2_AREAD                                                          \
  do {                                                                    \
    a2h0 = *reinterpret_cast<const half8*>(&afrag[aeU2 + lane * 8]);      \
    a2h1 = *reinterpret_cast<const half8*>(&afrag[aeU2 + 512 + lane * 8]); \
  } while (0)

#define G2_ISSUE(B)                          \
  do {                                       \
    GLD16(T##B##0, vc[0] + koI2);            \
    GLD16(T##B##1, vc[1] + koI2);            \
    GLD16(T##B##2, vc[2] + koI2);            \
    GLD16(T##B##3, vc[3] + koI2);            \
    GLD16(T##B##4, vc[4] + koI2);            \
    GLD16(T##B##5, vc[5] + koI2);            \
    GLD16(T##B##6, vc[6] + koI2);            \
    GLD16(T##B##7, vc[7] + koI2);            \
    GLD16(T##B##8, vc[8] + koI2);            \
  } while (0)

#define G2_FMA(B)                                              \
  do {                                                         \
    __builtin_amdgcn_s_setprio(1);                             \
    acc2[0][0] = MFMA16(a2h0, asH8(T##B##0), acc2[0][0]);      \
    acc2[1][0] = MFMA16(a2h1, asH8(T##B##0), acc2[1][0]);      \
    acc2[0][1] = MFMA16(a2h0, asH8(T##B##1), acc2[0][1]);      \
    acc2[1][1] = MFMA16(a2h1, asH8(T##B##1), acc2[1][1]);      \
    acc2[0][2] = MFMA16(a2h0, asH8(T##B##2), acc2[0][2]);      \
    acc2[1][2] = MFMA16(a2h1, asH8(T##B##2), acc2[1][2]);      \
    acc2[0][3] = MFMA16(a2h0, asH8(T##B##3), acc2[0][3]);      \
    acc2[1][3] = MFMA16(a2h1, asH8(T##B##3), acc2[1][3]);      \
    acc2[0][4] = MFMA16(a2h0, asH8(T##B##4), acc2[0][4]);      \
    acc2[1][4] = MFMA16(a2h1, asH8(T##B##4), acc2[1][4]);      \
    acc2[0][5] = MFMA16(a2h0, asH8(T##B##5), acc2[0][5]);      \
    acc2[1][5] = MFMA16(a2h1, asH8(T##B##5), acc2[1][5]);      \
    acc2[0][6] = MFMA16(a2h0, asH8(T##B##6), acc2[0][6]);      \
    acc2[1][6] = MFMA16(a2h1, asH8(T##B##6), acc2[1][6]);      \
    acc2[0][7] = MFMA16(a2h0, asH8(T##B##7), acc2[0][7]);      \
    acc2[1][7] = MFMA16(a2h1, asH8(T##B##7), acc2[1][7]);      \
    acc2[0][8] = MFMA16(a2h0, asH8(T##B##8), acc2[0][8]);      \
    acc2[1][8] = MFMA16(a2h1, asH8(T##B##8), acc2[1][8]);      \
    __builtin_amdgcn_s_setprio(0);                             \
  } while (0)

    G2_ISSUE(0); ADVK2;
    G2_ISSUE(1); ADVK2;
    for (int u = 0; u < 4; ++u) {  // slots 0..11
      G2_AREAD; G2_ISSUE(2); VMW(18); G2_FMA(0); ADVK2; ADVA2;
      G2_AREAD; G2_ISSUE(0); VMW(18); G2_FMA(1); ADVK2; ADVA2;
      G2_AREAD; G2_ISSUE(1); VMW(18); G2_FMA(2); ADVK2; ADVA2;
    }
    // slots 12..15
    G2_AREAD; G2_ISSUE(2); VMW(18); G2_FMA(0); ADVK2; ADVA2;
    G2_AREAD; G2_ISSUE(0); VMW(18); G2_FMA(1); ADVA2;
    G2_AREAD; VMW(9); G2_FMA(2); ADVA2;
    G2_AREAD; VMW(0); G2_FMA(0);
  }

  // ---- epilogue: nontemporal stores ----
  {
    const int nbase = b * 4096 + h * 64 + w0;
#pragma unroll
    for (int rt = 0; rt < 2; ++rt)
#pragma unroll
      for (int nt = 0; nt < 9; ++nt)
#pragma unroll
        for (int r = 0; r < 4; ++r) {
          int p = rt * 16 + koct * 4 + r;
          int d = wv * 144 + l15 + nt * 16;
          __builtin_nontemporal_store(acc2[rt][nt][r], &out[(nbase + p) * 576 + d]);
        }
  }
}

extern "C" void kernel_launch(void* const* d_in, const int* in_sizes, int n_in,
                              void* d_out, int out_size, void* d_ws, size_t ws_size,
                              hipStream_t stream) {
  const float* x = (const float*)d_in[0];
  const float* memory = (const float*)d_in[1];
  const float* temperature = (const float*)d_in[2];
  float* out = (float*)d_out;
  _Float16* ws = (_Float16*)d_ws;  // needs 1,769,472 bytes

  prep_split<<<512, 576, 0, stream>>>(memory, ws);
  mem_branch_kernel<<<2048, 256, 0, stream>>>(x, temperature, ws, out);
}

// Round 6
// 421.531 us; speedup vs baseline: 1.0877x; 1.0877x over previous
//
#include <hip/hip_runtime.h>

typedef _Float16 half8 __attribute__((ext_vector_type(8)));
typedef float floatx4 __attribute__((ext_vector_type(4)));
typedef int intx4 __attribute__((ext_vector_type(4)));

#define MFMA16(a, b, c) __builtin_amdgcn_mfma_f32_16x16x32_f16(a, b, c, 0, 0, 0)

static __device__ __forceinline__ half8 asH8(intx4 v) {
  half8 r;
  __builtin_memcpy(&r, &v, 16);
  return r;
}

static constexpr int kC = 64, kH = 64, kW = 64;
static constexpr int kM = 512, kD = 576;  // D = C*9
// ws layout (f16 elements):
//   WS1 (GEMM1 B, hi/lo interleaved per k-octet): [m:512][k8:72][16]
//   WS2 (GEMM2 B, hi only): [d:576][m:512]
static constexpr int WS2 = 589824;
// total ws: 884736 f16 = 1,769,472 bytes

__global__ void prep_split(const float* __restrict__ mem, _Float16* __restrict__ ws) {
  const int m = blockIdx.x;   // 512
  const int d = threadIdx.x;  // 576
  float v = mem[m * kD + d];
  _Float16 hi = (_Float16)v;
  _Float16 lo = (_Float16)(v - (float)hi);
  ws[m * 1152 + ((d >> 3) << 4) + (d & 7)] = hi;
  ws[m * 1152 + ((d >> 3) << 4) + (d & 7) + 8] = lo;
  ws[WS2 + d * 512 + m] = hi;
}

// One block: 32 pixels (b, h, w0..w0+31). 4 waves. 3 blocks/CU (LDS ~39KB, regs <=170).
__global__ __launch_bounds__(256, 3) void mem_branch_kernel(
    const float* __restrict__ x, const float* __restrict__ temperature,
    const _Float16* __restrict__ ws, float* __restrict__ out) {
  // A-hi fragments: [36 combos (kt*2+rt)][64 lanes][8 f16] = 36,864 B.
  // Later aliased by att-hi fragments: [32 combos][64][8] (32,768 B).
  __shared__ __align__(16) _Float16 afrag[36 * 64 * 8];
  __shared__ __align__(16) int tab[kD];  // A-build table; reused as red arrays after
  float* red_max = (float*)tab;          // [4][32]
  float* red_sum = (float*)tab + 128;    // [4][32]

  const int tid = threadIdx.x;
  const int lane = tid & 63;
  const int wv = tid >> 6;
  const int l15 = lane & 15;
  const int koct = lane >> 4;  // 0..3
  const int bx = blockIdx.x;
  const int b = bx >> 7;
  const int h = (bx >> 1) & 63;
  const int w0 = (bx & 1) << 5;

  const float sfac = temperature[0] * 0.060112293370373475f;  // (1/24)*log2(e)
  const _Float16* wsp = ws;

  for (int d = tid; d < kD; d += 256) {
    int c = d / 9, r9 = d % 9, kh = r9 / 3, kw = r9 % 3;
    tab[d] = (c << 12) + (kh << 6) + kw + (kh << 20) + (kw << 24);
  }
  __syncthreads();

  // ---- build patch A-hi fragments directly in fragment layout ----
  {
    const int base0 = ((b * kC) * kH + (h - 1)) * kW + (w0 - 1);
    for (int combo = wv; combo < 36; combo += 4) {
      const int kt = combo >> 1, rt = combo & 1;
      const int pp = rt * 16 + l15;  // pixel 0..31
      const int dbase = kt * 32 + koct * 8;
      intx4 t0 = *reinterpret_cast<const intx4*>(&tab[dbase]);
      intx4 t1 = *reinterpret_cast<const intx4*>(&tab[dbase + 4]);
      half8 hv;
#pragma unroll
      for (int j = 0; j < 8; ++j) {
        int t = (j < 4) ? t0[j] : t1[j - 4];
        int off = t & 0xFFFFF;
        int kh = (t >> 20) & 15;
        int kw = (t >> 24) & 15;
        bool ok = ((unsigned)(h - 1 + kh) < 64u) && ((unsigned)(w0 + pp - 1 + kw) < 64u);
        int idx = ok ? (base0 + pp + off) : 0;
        float v = x[idx];
        v = ok ? v : 0.0f;
        hv[j] = (_Float16)v;
      }
      *reinterpret_cast<half8*>(&afrag[combo * 512 + lane * 8]) = hv;
    }
  }
  __syncthreads();

// ---- asm helpers ----
#define GLD16(dst, voff) \
  asm volatile("global_load_dwordx4 %0, %1, %2 offset:0" : "=v"(dst) : "v"(voff), "s"(wsp))
#define GLD16O(dst, voff) \
  asm volatile("global_load_dwordx4 %0, %1, %2 offset:16" : "=v"(dst) : "v"(voff), "s"(wsp))
#define VMW(N)                                            \
  do {                                                    \
    asm volatile("s_waitcnt vmcnt(" #N ")" ::: "memory"); \
    __builtin_amdgcn_sched_barrier(0);                    \
  } while (0)

  // ---- GEMM1 (2-term: a_hi*(b_hi+b_lo)): wave owns m in [wv*128, +128).
  // Ring-4 bufs of 2-mt groups (4 x intx4 each), prefetch distance 3 groups.
  floatx4 acc[2][8];
  const floatx4 zed = {0.0f, 0.0f, 0.0f, 0.0f};
#pragma unroll
  for (int rt = 0; rt < 2; ++rt)
#pragma unroll
    for (int mt = 0; mt < 8; ++mt) acc[rt][mt] = zed;
  {
    const int mrow = wv * 128 + l15;
    int voffA[8];
#pragma unroll
    for (int mt = 0; mt < 8; ++mt) voffA[mt] = (mrow + mt * 16) * 2304 + koct * 32;
    intx4 R00, R01, R02, R03, R10, R11, R12, R13;
    intx4 R20, R21, R22, R23, R30, R31, R32, R33;
    half8 ah0, ah1;

#define G1_AREAD(KT)                                                               \
  do {                                                                             \
    ah0 = *reinterpret_cast<const half8*>(&afrag[((KT)*2 + 0) * 512 + lane * 8]);  \
    ah1 = *reinterpret_cast<const half8*>(&afrag[((KT)*2 + 1) * 512 + lane * 8]);  \
  } while (0)

#define G1_ISSUE(B, P)                     \
  do {                                     \
    GLD16(R##B##0, voffA[2 * (P)]);        \
    GLD16O(R##B##1, voffA[2 * (P)]);       \
    GLD16(R##B##2, voffA[2 * (P) + 1]);    \
    GLD16O(R##B##3, voffA[2 * (P) + 1]);   \
    voffA[2 * (P)] += 128;                 \
    voffA[2 * (P) + 1] += 128;             \
  } while (0)

#define G1_FMA(B, P)                                                       \
  do {                                                                     \
    const int m0 = 2 * (P), m1 = m0 + 1;                                   \
    __builtin_amdgcn_s_setprio(1);                                         \
    acc[0][m0] = MFMA16(ah0, asH8(R##B##0), acc[0][m0]);                   \
    acc[1][m0] = MFMA16(ah1, asH8(R##B##0), acc[1][m0]);                   \
    acc[0][m1] = MFMA16(ah0, asH8(R##B##2), acc[0][m1]);                   \
    acc[1][m1] = MFMA16(ah1, asH8(R##B##2), acc[1][m1]);                   \
    acc[0][m0] = MFMA16(ah0, asH8(R##B##1), acc[0][m0]);                   \
    acc[1][m0] = MFMA16(ah1, asH8(R##B##1), acc[1][m0]);                   \
    acc[0][m1] = MFMA16(ah0, asH8(R##B##3), acc[0][m1]);                   \
    acc[1][m1] = MFMA16(ah1, asH8(R##B##3), acc[1][m1]);                   \
    __builtin_amdgcn_s_setprio(0);                                         \
  } while (0)

    G1_ISSUE(0, 0);
    G1_ISSUE(1, 1);
    G1_ISSUE(2, 2);
    for (int kt = 0; kt < 17; ++kt) {
      G1_AREAD(kt);
      G1_ISSUE(3, 3); VMW(12); G1_FMA(0, 0);
      G1_ISSUE(0, 0); VMW(12); G1_FMA(1, 1);
      G1_ISSUE(1, 1); VMW(12); G1_FMA(2, 2);
      G1_ISSUE(2, 2); VMW(12); G1_FMA(3, 3);
    }
    G1_AREAD(17);
    G1_ISSUE(3, 3); VMW(12); G1_FMA(0, 0);
    VMW(8); G1_FMA(1, 1);
    VMW(4); G1_FMA(2, 2);
    VMW(0); G1_FMA(3, 3);
  }

  // ---- softmax over m (512); lane: p = rt*16+koct*4+r, m = wv*128+mt*16+l15 ----
  float pm[2][4], ps[2][4], gm[2][4], rinv[2][4];
#pragma unroll
  for (int rt = 0; rt < 2; ++rt)
#pragma unroll
    for (int r = 0; r < 4; ++r) {
      float v = acc[rt][0][r];
#pragma unroll
      for (int mt = 1; mt < 8; ++mt) v = fmaxf(v, acc[rt][mt][r]);
      pm[rt][r] = v;
    }
#pragma unroll
  for (int off = 1; off < 16; off <<= 1)
#pragma unroll
    for (int rt = 0; rt < 2; ++rt)
#pragma unroll
      for (int r = 0; r < 4; ++r) pm[rt][r] = fmaxf(pm[rt][r], __shfl_xor(pm[rt][r], off, 64));
  if (l15 == 0) {
#pragma unroll
    for (int rt = 0; rt < 2; ++rt)
#pragma unroll
      for (int r = 0; r < 4; ++r) red_max[wv * 32 + rt * 16 + koct * 4 + r] = pm[rt][r];
  }
  __syncthreads();
#pragma unroll
  for (int rt = 0; rt < 2; ++rt)
#pragma unroll
    for (int r = 0; r < 4; ++r) {
      int p = rt * 16 + koct * 4 + r;
      gm[rt][r] = fmaxf(fmaxf(red_max[p], red_max[32 + p]), fmaxf(red_max[64 + p], red_max[96 + p]));
      ps[rt][r] = 0.0f;
    }
#pragma unroll
  for (int rt = 0; rt < 2; ++rt)
#pragma unroll
    for (int mt = 0; mt < 8; ++mt)
#pragma unroll
      for (int r = 0; r < 4; ++r) {
        float e = exp2f((acc[rt][mt][r] - gm[rt][r]) * sfac);
        acc[rt][mt][r] = e;
        ps[rt][r] += e;
      }
#pragma unroll
  for (int off = 1; off < 16; off <<= 1)
#pragma unroll
    for (int rt = 0; rt < 2; ++rt)
#pragma unroll
      for (int r = 0; r < 4; ++r) ps[rt][r] += __shfl_xor(ps[rt][r], off, 64);
  if (l15 == 0) {
#pragma unroll
    for (int rt = 0; rt < 2; ++rt)
#pragma unroll
      for (int r = 0; r < 4; ++r) red_sum[wv * 32 + rt * 16 + koct * 4 + r] = ps[rt][r];
  }
  __syncthreads();
#pragma unroll
  for (int rt = 0; rt < 2; ++rt)
#pragma unroll
    for (int r = 0; r < 4; ++r) {
      int p = rt * 16 + koct * 4 + r;
      rinv[rt][r] = 1.0f / (red_sum[p] + red_sum[32 + p] + red_sum[64 + p] + red_sum[96 + p]);
    }
  // write att-hi fragments into (aliased) afrag
#pragma unroll
  for (int rt = 0; rt < 2; ++rt)
#pragma unroll
    for (int mt = 0; mt < 8; ++mt)
#pragma unroll
      for (int r = 0; r < 4; ++r) {
        float a = acc[rt][mt][r] * rinv[rt][r];
        _Float16 hi = (_Float16)a;
        int m = wv * 128 + mt * 16 + l15;
        int lf = (koct * 4 + r) + (((m >> 3) & 3) << 4);
        int idxe = ((((m >> 5) << 1) + rt) * 64 + lf) * 8 + (m & 7);
        afrag[idxe] = hi;
      }
  __syncthreads();

  // ---- GEMM2 (hi-only): out[32][576] = att_hi @ mem_hi; wave owns d in [wv*144,+144).
  // Ring-3 bufs of 3-nt groups, prefetch distance 2 groups.
  floatx4 acc2[2][9];
#pragma unroll
  for (int rt = 0; rt < 2; ++rt)
#pragma unroll
    for (int nt = 0; nt < 9; ++nt) acc2[rt][nt] = zed;
  {
    const int d0 = wv * 144 + l15;
    int voffB[9];
#pragma unroll
    for (int nt = 0; nt < 9; ++nt) voffB[nt] = WS2 * 2 + (d0 + nt * 16) * 1024 + koct * 16;
    intx4 S00, S01, S02, S10, S11, S12, S20, S21, S22;
    half8 a2h0, a2h1;

#define G2_AREAD(KT)                                                                \
  do {                                                                              \
    a2h0 = *reinterpret_cast<const half8*>(&afrag[((KT)*2 + 0) * 512 + lane * 8]);  \
    a2h1 = *reinterpret_cast<const half8*>(&afrag[((KT)*2 + 1) * 512 + lane * 8]);  \
  } while (0)

#define G2_ISSUE(B, T)                  \
  do {                                  \
    GLD16(S##B##0, voffB[3 * (T)]);     \
    GLD16(S##B##1, voffB[3 * (T) + 1]); \
    GLD16(S##B##2, voffB[3 * (T) + 2]); \
    voffB[3 * (T)] += 64;               \
    voffB[3 * (T) + 1] += 64;           \
    voffB[3 * (T) + 2] += 64;           \
  } while (0)

#define G2_FMA(B, T)                                                          \
  do {                                                                        \
    __builtin_amdgcn_s_setprio(1);                                            \
    acc2[0][3 * (T)] = MFMA16(a2h0, asH8(S##B##0), acc2[0][3 * (T)]);         \
    acc2[1][3 * (T)] = MFMA16(a2h1, asH8(S##B##0), acc2[1][3 * (T)]);         \
    acc2[0][3 * (T) + 1] = MFMA16(a2h0, asH8(S##B##1), acc2[0][3 * (T) + 1]); \
    acc2[1][3 * (T) + 1] = MFMA16(a2h1, asH8(S##B##1), acc2[1][3 * (T) + 1]); \
    acc2[0][3 * (T) + 2] = MFMA16(a2h0, asH8(S##B##2), acc2[0][3 * (T) + 2]); \
    acc2[1][3 * (T) + 2] = MFMA16(a2h1, asH8(S##B##2), acc2[1][3 * (T) + 2]); \
    __builtin_amdgcn_s_setprio(0);                                            \
  } while (0)

    G2_ISSUE(0, 0);
    G2_ISSUE(1, 1);
    for (int kt2 = 0; kt2 < 15; ++kt2) {
      G2_AREAD(kt2);
      G2_ISSUE(2, 2); VMW(6); G2_FMA(0, 0);
      G2_ISSUE(0, 0); VMW(6); G2_FMA(1, 1);
      G2_ISSUE(1, 1); VMW(6); G2_FMA(2, 2);
    }
    G2_AREAD(15);
    G2_ISSUE(2, 2); VMW(6); G2_FMA(0, 0);
    VMW(3); G2_FMA(1, 1);
    VMW(0); G2_FMA(2, 2);
  }

  // ---- epilogue: nontemporal stores ----
  {
    const int nbase = b * 4096 + h * 64 + w0;
#pragma unroll
    for (int rt = 0; rt < 2; ++rt)
#pragma unroll
      for (int nt = 0; nt < 9; ++nt)
#pragma unroll
        for (int r = 0; r < 4; ++r) {
          int p = rt * 16 + koct * 4 + r;
          int d = wv * 144 + l15 + nt * 16;
          __builtin_nontemporal_store(acc2[rt][nt][r], &out[(nbase + p) * 576 + d]);
        }
  }
}

extern "C" void kernel_launch(void* const* d_in, const int* in_sizes, int n_in,
                              void* d_out, int out_size, void* d_ws, size_t ws_size,
                              hipStream_t stream) {
  const float* x = (const float*)d_in[0];
  const float* memory = (const float*)d_in[1];
  const float* temperature = (const float*)d_in[2];
  float* out = (float*)d_out;
  _Float16* ws = (_Float16*)d_ws;  // needs 1,769,472 bytes

  prep_split<<<512, 576, 0, stream>>>(memory, ws);
  mem_branch_kernel<<<2048, 256, 0, stream>>>(x, temperature, ws, out);
}

// Round 7
// 229.366 us; speedup vs baseline: 1.9991x; 1.8378x over previous
//
#include <hip/hip_runtime.h>

typedef _Float16 half8 __attribute__((ext_vector_type(8)));
typedef float floatx4 __attribute__((ext_vector_type(4)));
typedef int intx4 __attribute__((ext_vector_type(4)));

#define MFMA16(a, b, c) __builtin_amdgcn_mfma_f32_16x16x32_f16(a, b, c, 0, 0, 0)

static constexpr int kM = 512, kD = 576;
// ws layout (f16 elements):
//   WS1 (GEMM1 B, hi/lo interleaved per k-octet): [m:512][k8:72][16] -> 2304 B/row
//   WS2 (GEMM2 B, hi only): [d:576][m:512] -> 1024 B/row
static constexpr int WS2 = 589824;
// total ws: 884736 f16 = 1,769,472 bytes

__global__ void prep_split(const float* __restrict__ mem, _Float16* __restrict__ ws) {
  const int m = blockIdx.x;   // 512
  const int d = threadIdx.x;  // 576
  float v = mem[m * kD + d];
  _Float16 hi = (_Float16)v;
  _Float16 lo = (_Float16)(v - (float)hi);
  ws[m * 1152 + ((d >> 3) << 4) + (d & 7)] = hi;
  ws[m * 1152 + ((d >> 3) << 4) + (d & 7) + 8] = lo;
  ws[WS2 + d * 512 + m] = hi;
}

// global->LDS direct (16B/lane, dest = uniform base + lane*16)
#define GLD_LDS16(gp, lp)                                                          \
  __builtin_amdgcn_global_load_lds((__attribute__((address_space(1))) void*)(gp),  \
                                   (__attribute__((address_space(3))) void*)(lp),  \
                                   16, 0, 0)
#define VMW0 asm volatile("s_waitcnt vmcnt(0)" ::: "memory")

// One block: 64 pixels = one (b,h) row. 512 threads / 8 waves. 1 block/CU.
__global__ __launch_bounds__(512, 2) void mem_branch_kernel(
    const float* __restrict__ x, const float* __restrict__ temperature,
    const _Float16* __restrict__ ws, float* __restrict__ out) {
  // G1 A-frags: [72 combos (kt*4+pt)][64 lanes][8 f16] = 73,728 B.
  // Reused for att-frags: [64 combos (kt2*4+pt)][64][8] = 65,536 B.
  __shared__ __align__(16) _Float16 afrag[36864];
  __shared__ __align__(16) unsigned char blds[65536];  // B staging (G1:64KB, G2:36KB)
  __shared__ float redm[512];
  __shared__ float reds[512];
  __shared__ __align__(16) int tab[kD];

  const int tid = threadIdx.x;
  const int lane = tid & 63;
  const int wv = tid >> 6;  // 0..7
  const int l15 = lane & 15;
  const int koct = lane >> 4;  // 0..3
  const int bx = blockIdx.x;   // 1024
  const int b = bx >> 6;
  const int h = bx & 63;

  const float sfac = temperature[0] * 0.060112293370373475f;  // (1/24)*log2(e)
  const unsigned char* wsb = (const unsigned char*)ws;

  for (int d = tid; d < kD; d += 512) {
    int c = d / 9, r9 = d % 9, kh = r9 / 3, kw = r9 % 3;
    tab[d] = (c << 12) + (kh << 6) + kw + (kh << 20) + (kw << 24);
  }
  __syncthreads();

  // ---- build A-hi fragments (64 px = full w row) in fragment layout ----
  {
    const int base0 = (b * 4096 + (h - 1)) * 64 - 1;
    for (int i = 0; i < 9; ++i) {
      const int combo = i * 8 + wv;  // 0..71 = kt*4 + pt
      const int kt = combo >> 2, pt = combo & 3;
      const int pp = pt * 16 + l15;  // px = w
      const int dbase = kt * 32 + koct * 8;
      intx4 t0 = *reinterpret_cast<const intx4*>(&tab[dbase]);
      intx4 t1 = *reinterpret_cast<const intx4*>(&tab[dbase + 4]);
      half8 hv;
#pragma unroll
      for (int j = 0; j < 8; ++j) {
        int t = (j < 4) ? t0[j] : t1[j - 4];
        int off = t & 0xFFFFF;
        int kh = (t >> 20) & 15;
        int kw = (t >> 24) & 15;
        bool ok = ((unsigned)(h - 1 + kh) < 64u) && ((unsigned)(pp - 1 + kw) < 64u);
        int idx = ok ? (base0 + pp + off) : 0;
        float v = x[idx];
        v = ok ? v : 0.0f;
        hv[j] = (_Float16)v;
      }
      *reinterpret_cast<half8*>(&afrag[combo * 512 + lane * 8]) = hv;
    }
  }

  // ---- GEMM1 (2-term hi*(hi+lo)): wave owns m-range [wv*64, +64), all 64 px ----
  floatx4 acc[4][4];  // [pt][mt]
  const floatx4 zed = {0.0f, 0.0f, 0.0f, 0.0f};
#pragma unroll
  for (int pt = 0; pt < 4; ++pt)
#pragma unroll
    for (int mt = 0; mt < 4; ++mt) acc[pt][mt] = zed;
  {
    // per-call pre-swizzled global source base (bytes); LDS row m: 128B, slot ^= (m&7)<<4
    int sbase[8];
#pragma unroll
    for (int ch = 0; ch < 8; ++ch) {
      int o = (wv * 8 + ch) * 1024 + lane * 16;
      int m = o >> 7, inner = o & 127;
      sbase[ch] = m * 2304 + (inner ^ ((m & 7) << 4));
    }
    for (int kt = 0; kt < 18; ++kt) {
      __syncthreads();  // previous compute done -> safe to overwrite blds
#pragma unroll
      for (int ch = 0; ch < 8; ++ch)
        GLD_LDS16(wsb + (sbase[ch] + kt * 128), blds + (wv * 8 + ch) * 1024);
      // overlap A-frag LDS reads with staging latency (afrag is stable)
      half8 aa0 = *reinterpret_cast<const half8*>(&afrag[(kt * 4 + 0) * 512 + lane * 8]);
      half8 aa1 = *reinterpret_cast<const half8*>(&afrag[(kt * 4 + 1) * 512 + lane * 8]);
      half8 aa2 = *reinterpret_cast<const half8*>(&afrag[(kt * 4 + 2) * 512 + lane * 8]);
      half8 aa3 = *reinterpret_cast<const half8*>(&afrag[(kt * 4 + 3) * 512 + lane * 8]);
      VMW0;
      __syncthreads();  // staged B visible to all
#pragma unroll
      for (int mt = 0; mt < 4; ++mt) {
        const int mr = wv * 64 + mt * 16 + l15;
        const int swz = (mr & 7) << 4;
        const half8 bh =
            *reinterpret_cast<const half8*>(blds + mr * 128 + ((koct * 32) ^ swz));
        const half8 bl =
            *reinterpret_cast<const half8*>(blds + mr * 128 + ((koct * 32 + 16) ^ swz));
        __builtin_amdgcn_s_setprio(1);
        acc[0][mt] = MFMA16(aa0, bh, acc[0][mt]);
        acc[1][mt] = MFMA16(aa1, bh, acc[1][mt]);
        acc[2][mt] = MFMA16(aa2, bh, acc[2][mt]);
        acc[3][mt] = MFMA16(aa3, bh, acc[3][mt]);
        acc[0][mt] = MFMA16(aa0, bl, acc[0][mt]);
        acc[1][mt] = MFMA16(aa1, bl, acc[1][mt]);
        acc[2][mt] = MFMA16(aa2, bl, acc[2][mt]);
        acc[3][mt] = MFMA16(aa3, bl, acc[3][mt]);
        __builtin_amdgcn_s_setprio(0);
      }
    }
  }

  // ---- softmax over m=512; lane holds px = pt*16+koct*4+r, m = wv*64+mt*16+l15 ----
  float pm[4][4], ps[4][4];  // pm -> global max; ps -> 1/sum
#pragma unroll
  for (int pt = 0; pt < 4; ++pt)
#pragma unroll
    for (int r = 0; r < 4; ++r) {
      float v = acc[pt][0][r];
#pragma unroll
      for (int mt = 1; mt < 4; ++mt) v = fmaxf(v, acc[pt][mt][r]);
      pm[pt][r] = v;
    }
#pragma unroll
  for (int off = 1; off < 16; off <<= 1)
#pragma unroll
    for (int pt = 0; pt < 4; ++pt)
#pragma unroll
      for (int r = 0; r < 4; ++r) pm[pt][r] = fmaxf(pm[pt][r], __shfl_xor(pm[pt][r], off, 64));
  if (l15 == 0) {
#pragma unroll
    for (int pt = 0; pt < 4; ++pt)
#pragma unroll
      for (int r = 0; r < 4; ++r) redm[wv * 64 + pt * 16 + koct * 4 + r] = pm[pt][r];
  }
  __syncthreads();
#pragma unroll
  for (int pt = 0; pt < 4; ++pt)
#pragma unroll
    for (int r = 0; r < 4; ++r) {
      const int p = pt * 16 + koct * 4 + r;
      float g = redm[p];
#pragma unroll
      for (int w = 1; w < 8; ++w) g = fmaxf(g, redm[w * 64 + p]);
      pm[pt][r] = g;
      ps[pt][r] = 0.0f;
    }
#pragma unroll
  for (int pt = 0; pt < 4; ++pt)
#pragma unroll
    for (int mt = 0; mt < 4; ++mt)
#pragma unroll
      for (int r = 0; r < 4; ++r) {
        float e = exp2f((acc[pt][mt][r] - pm[pt][r]) * sfac);
        acc[pt][mt][r] = e;
        ps[pt][r] += e;
      }
#pragma unroll
  for (int off = 1; off < 16; off <<= 1)
#pragma unroll
    for (int pt = 0; pt < 4; ++pt)
#pragma unroll
      for (int r = 0; r < 4; ++r) ps[pt][r] += __shfl_xor(ps[pt][r], off, 64);
  if (l15 == 0) {
#pragma unroll
    for (int pt = 0; pt < 4; ++pt)
#pragma unroll
      for (int r = 0; r < 4; ++r) reds[wv * 64 + pt * 16 + koct * 4 + r] = ps[pt][r];
  }
  __syncthreads();
#pragma unroll
  for (int pt = 0; pt < 4; ++pt)
#pragma unroll
    for (int r = 0; r < 4; ++r) {
      const int p = pt * 16 + koct * 4 + r;
      float s = reds[p];
#pragma unroll
      for (int w = 1; w < 8; ++w) s += reds[w * 64 + p];
      ps[pt][r] = 1.0f / s;
    }
  // write att-hi fragments into (aliased) afrag: [kt2*4+pt][lane'][j']
#pragma unroll
  for (int pt = 0; pt < 4; ++pt)
#pragma unroll
    for (int mt = 0; mt < 4; ++mt)
#pragma unroll
      for (int r = 0; r < 4; ++r) {
        float a = acc[pt][mt][r] * ps[pt][r];
        const int m = wv * 64 + mt * 16 + l15;
        const int idxe = (((m >> 5) * 4 + pt) * 64 + ((m >> 3) & 3) * 16 + koct * 4 + r) * 8 + (m & 7);
        afrag[idxe] = (_Float16)a;
      }
  // (G2 loop-entry barrier orders these writes before any read)

  // ---- GEMM2 (hi-only): out[64][576] = att_hi @ mem_hi ----
  // wave owns d-tiles {wv*4..wv*4+3} and (wv<4 ? 32+wv : -)
  floatx4 acc2[5][4];  // [nt][pt]
#pragma unroll
  for (int nt = 0; nt < 5; ++nt)
#pragma unroll
    for (int pt = 0; pt < 4; ++pt) acc2[nt][pt] = zed;
  for (int kt2 = 0; kt2 < 16; ++kt2) {
    __syncthreads();
#pragma unroll
    for (int ch = 0; ch < 5; ++ch) {
      const int q = ch * 8 + wv;
      if (q < 36) {
        const int o = q * 1024 + lane * 16;
        const int dd = o >> 6, inner = o & 63;
        GLD_LDS16(wsb + (WS2 * 2 + dd * 1024 + kt2 * 64 + (inner ^ ((dd & 3) << 4))),
                  blds + q * 1024);
      }
    }
    half8 p0 = *reinterpret_cast<const half8*>(&afrag[((kt2 * 4 + 0) * 64 + lane) * 8]);
    half8 p1 = *reinterpret_cast<const half8*>(&afrag[((kt2 * 4 + 1) * 64 + lane) * 8]);
    half8 p2 = *reinterpret_cast<const half8*>(&afrag[((kt2 * 4 + 2) * 64 + lane) * 8]);
    half8 p3 = *reinterpret_cast<const half8*>(&afrag[((kt2 * 4 + 3) * 64 + lane) * 8]);
    VMW0;
    __syncthreads();
#pragma unroll
    for (int nt = 0; nt < 5; ++nt) {
      if (nt < 4 || wv < 4) {
        const int dtile = (nt < 4) ? (wv * 4 + nt) : (32 + wv);
        const int row = dtile * 16 + l15;
        const half8 bh =
            *reinterpret_cast<const half8*>(blds + row * 64 + ((koct * 16) ^ ((row & 3) << 4)));
        __builtin_amdgcn_s_setprio(1);
        acc2[nt][0] = MFMA16(p0, bh, acc2[nt][0]);
        acc2[nt][1] = MFMA16(p1, bh, acc2[nt][1]);
        acc2[nt][2] = MFMA16(p2, bh, acc2[nt][2]);
        acc2[nt][3] = MFMA16(p3, bh, acc2[nt][3]);
        __builtin_amdgcn_s_setprio(0);
      }
    }
  }

  // ---- epilogue: nontemporal stores ----
  {
    const int nbase = b * 4096 + h * 64;
#pragma unroll
    for (int nt = 0; nt < 5; ++nt) {
      if (nt < 4 || wv < 4) {
        const int dtile = (nt < 4) ? (wv * 4 + nt) : (32 + wv);
        const int d = dtile * 16 + l15;
#pragma unroll
        for (int pt = 0; pt < 4; ++pt)
#pragma unroll
          for (int r = 0; r < 4; ++r) {
            const int px = pt * 16 + koct * 4 + r;
            __builtin_nontemporal_store(acc2[nt][pt][r], &out[(nbase + px) * 576 + d]);
          }
      }
    }
  }
}

extern "C" void kernel_launch(void* const* d_in, const int* in_sizes, int n_in,
                              void* d_out, int out_size, void* d_ws, size_t ws_size,
                              hipStream_t stream) {
  const float* x = (const float*)d_in[0];
  const float* memory = (const float*)d_in[1];
  const float* temperature = (const float*)d_in[2];
  float* out = (float*)d_out;
  _Float16* ws = (_Float16*)d_ws;  // needs 1,769,472 bytes

  prep_split<<<512, 576, 0, stream>>>(memory, ws);
  mem_branch_kernel<<<1024, 512, 0, stream>>>(x, temperature, ws, out);
}